// Round 13
// baseline (225.240 us; speedup 1.0000x reference)
//
#include <hip/hip_runtime.h>

#define THREADS 256
#define G1 1024         // partition blocks (4 blocks/CU for latency hiding)
#define MAXNB 4096      // max coarse buckets (n <= 512k)

using bf16x8 = __attribute__((ext_vector_type(8))) short;
using f32x4 = __attribute__((ext_vector_type(4))) float;

// bf16 helpers (self-contained, RNE)
static __device__ __forceinline__ unsigned short f2bf(float f) {
  unsigned u = __float_as_uint(f);
  unsigned r = (u + 0x7fff + ((u >> 16) & 1)) >> 16;
  return (unsigned short)r;
}
static __device__ __forceinline__ float bflo(unsigned w) {
  return __uint_as_float(w << 16);
}
static __device__ __forceinline__ float bfhi(unsigned w) {
  return __uint_as_float(w & 0xffff0000u);
}
static __device__ __forceinline__ unsigned pk2(float a, float b) {
  return (unsigned)f2bf(a) | ((unsigned)f2bf(b) << 16);
}

// ======================= scan machinery (chunk=4096, 16/thread) ====================

__global__ void k_scan_chunk(const int* __restrict__ cnt, int* __restrict__ rp,
                             int* __restrict__ bsum, int m) {
  __shared__ int s[256];
  int b = blockIdx.x, t = threadIdx.x;
  int base = b * 4096 + t * 16;
  int v[16];
  int sum = 0;
#pragma unroll
  for (int k = 0; k < 16; ++k) {
    int i = base + k;
    v[k] = (i < m) ? cnt[i] : 0;
    sum += v[k];
  }
  s[t] = sum;
  __syncthreads();
  int mine = sum;
  for (int off = 1; off < 256; off <<= 1) {
    int y = (t >= off) ? s[t - off] : 0;
    __syncthreads();
    s[t] += y;
    __syncthreads();
  }
  int run = s[t] - mine;
  if (t == 255) bsum[b] = s[255];
#pragma unroll
  for (int k = 0; k < 16; ++k) {
    int i = base + k;
    if (i <= m) rp[i] = run;
    run += v[k];
  }
}

__global__ void k_scan_bsum(int* __restrict__ bsum, int nb) {
  __shared__ int s[256];
  int t = threadIdx.x;
  int v = (t < nb) ? bsum[t] : 0;
  s[t] = v;
  __syncthreads();
  for (int off = 1; off < 256; off <<= 1) {
    int y = (t >= off) ? s[t - off] : 0;
    __syncthreads();
    s[t] += y;
    __syncthreads();
  }
  if (t < nb) bsum[t] = s[t] - v;
}

__global__ void k_add(int* __restrict__ a, const int* __restrict__ bsum, int m) {
  int i = blockIdx.x * blockDim.x + threadIdx.x;
  if (i < m) a[i] += bsum[i >> 12];
}

// ======================= misc init =======================

__global__ void k_zrow(unsigned* __restrict__ h1b, unsigned* __restrict__ h2b, int n) {
  int t = threadIdx.x;
  if (t < 16) h1b[(size_t)n * 32 + t] = 0u;
  else if (t < 24) h2b[(size_t)n * 16 + (t - 16)] = 0u;
}

// ======================= CSR build: two-phase partition, LDS atomics only ===========

__launch_bounds__(256)
__global__ void k_pcount(const int* __restrict__ dst, int* __restrict__ C, int e,
                         int NB, int chunk) {
  __shared__ int h[MAXNB];
  int blk = blockIdx.x, t = threadIdx.x;
  for (int i = t; i < NB; i += 256) h[i] = 0;
  __syncthreads();
  int beg = blk * chunk;
  int stop = min(e, beg + chunk);
  for (int j = beg + t; j < stop; j += 256) atomicAdd(&h[dst[j] >> 7], 1);
  __syncthreads();
  for (int i = t; i < NB; i += 256) C[i * G1 + blk] = h[i];
}

__launch_bounds__(256)
__global__ void k_partition(const int* __restrict__ src, const int* __restrict__ dst,
                            const int* __restrict__ Cs, int* __restrict__ bpack, int e,
                            int NB, int chunk) {
  __shared__ int cur[MAXNB];
  int blk = blockIdx.x, t = threadIdx.x;
  for (int i = t; i < NB; i += 256) cur[i] = Cs[i * G1 + blk];
  __syncthreads();
  int beg = blk * chunk;
  int stop = min(e, beg + chunk);
  for (int j = beg + t; j < stop; j += 256) {
    int d = dst[j];
    int b = d >> 7;
    int pos = atomicAdd(&cur[b], 1);
    bpack[pos] = (src[j] << 7) | (d & 127);
  }
}

__launch_bounds__(256)
__global__ void k_bucket_csr(const int* __restrict__ bpack, const int* __restrict__ Cs,
                             int* __restrict__ rp, float* __restrict__ dinv,
                             int* __restrict__ csr_src, int n, int e, int NB) {
  __shared__ int cl[128];
  __shared__ int cur[128];
  int blk = blockIdx.x, t = threadIdx.x;
  int base = Cs[blk * G1];
  int end = (blk == NB - 1) ? e : Cs[(blk + 1) * G1];
  if (t < 128) cl[t] = 0;
  __syncthreads();
  for (int j = base + t; j < end; j += 256) atomicAdd(&cl[bpack[j] & 127], 1);
  __syncthreads();
  int own = (t < 128) ? cl[t] : 0;
  for (int off = 1; off < 128; off <<= 1) {
    int y = (t >= off && t < 128) ? cl[t - off] : 0;
    __syncthreads();
    if (t < 128) cl[t] += y;
    __syncthreads();
  }
  if (t < 128) {
    int excl = cl[t] - own;
    int v = (blk << 7) + t;
    if (v < n) {
      rp[v] = base + excl;
      dinv[v] = rsqrtf((float)own + 1.0f);
    }
    cur[t] = base + excl;
  }
  __syncthreads();
  for (int j = base + t; j < end; j += 256) {
    int p = bpack[j];
    int pos = atomicAdd(&cur[p & 127], 1);
    csr_src[pos] = p >> 7;
  }
  if (blk == 0 && t == 0) rp[n] = e;
}

// ======================= GEMM1 (MFMA): h1b[n][64](bf16) = dinv[r]*(x @ W1^T) ======

__launch_bounds__(256)
__global__ void k_gemm1(const float* __restrict__ x, const float* __restrict__ W1,
                        const float* __restrict__ dinv, unsigned short* __restrict__ h1b,
                        int n) {
  __shared__ uint4 sXb[64 * 16];                       // 16 KB
  __shared__ uint4 sWb[64 * 16];                       // 16 KB
  __shared__ __align__(16) unsigned short sOut[64 * 64];  // 8 KB
  int t = threadIdx.x;
  const float4* x4 = (const float4*)x;
  const float4* W14 = (const float4*)W1;
  int rbase = blockIdx.x * 64;
#pragma unroll
  for (int p = 0; p < 4; ++p) {
    int q = t + 256 * p;
    int r = q >> 4, s = q & 15;
    int gr = rbase + r;
    float4 v0 = make_float4(0.f, 0.f, 0.f, 0.f), v1 = v0;
    if (gr < n) {
      v0 = x4[(size_t)gr * 32 + s * 2];
      v1 = x4[(size_t)gr * 32 + s * 2 + 1];
    }
    uint4 pk;
    pk.x = pk2(v0.x, v0.y);
    pk.y = pk2(v0.z, v0.w);
    pk.z = pk2(v1.x, v1.y);
    pk.w = pk2(v1.z, v1.w);
    sXb[r * 16 + (s ^ (r & 15))] = pk;
  }
#pragma unroll
  for (int p = 0; p < 4; ++p) {
    int q = t + 256 * p;
    int c = q >> 4, s = q & 15;
    float4 v0 = W14[c * 32 + s * 2];
    float4 v1 = W14[c * 32 + s * 2 + 1];
    uint4 pk;
    pk.x = pk2(v0.x, v0.y);
    pk.y = pk2(v0.z, v0.w);
    pk.z = pk2(v1.x, v1.y);
    pk.w = pk2(v1.z, v1.w);
    sWb[c * 16 + (s ^ (c & 15))] = pk;
  }
  __syncthreads();
  int lane = t & 63;
  int w = t >> 6;
  int l16 = lane & 15, quad = lane >> 4;
  int arow = w * 16 + l16;
  f32x4 acc0 = {0.f, 0.f, 0.f, 0.f};
  f32x4 acc1 = {0.f, 0.f, 0.f, 0.f};
  f32x4 acc2 = {0.f, 0.f, 0.f, 0.f};
  f32x4 acc3 = {0.f, 0.f, 0.f, 0.f};
#pragma unroll
  for (int kc = 0; kc < 4; ++kc) {
    int slot = kc * 4 + quad;
    uint4 ua = sXb[arow * 16 + (slot ^ (arow & 15))];
    bf16x8 a = *(bf16x8*)&ua;
    uint4 ub0 = sWb[(0 + l16) * 16 + (slot ^ l16)];
    uint4 ub1 = sWb[(16 + l16) * 16 + (slot ^ l16)];
    uint4 ub2 = sWb[(32 + l16) * 16 + (slot ^ l16)];
    uint4 ub3 = sWb[(48 + l16) * 16 + (slot ^ l16)];
    acc0 = __builtin_amdgcn_mfma_f32_16x16x32_bf16(a, *(bf16x8*)&ub0, acc0, 0, 0, 0);
    acc1 = __builtin_amdgcn_mfma_f32_16x16x32_bf16(a, *(bf16x8*)&ub1, acc1, 0, 0, 0);
    acc2 = __builtin_amdgcn_mfma_f32_16x16x32_bf16(a, *(bf16x8*)&ub2, acc2, 0, 0, 0);
    acc3 = __builtin_amdgcn_mfma_f32_16x16x32_bf16(a, *(bf16x8*)&ub3, acc3, 0, 0, 0);
  }
  float dvr[4];
#pragma unroll
  for (int r = 0; r < 4; ++r) {
    int grow = rbase + w * 16 + quad * 4 + r;
    dvr[r] = (grow < n) ? dinv[grow] : 0.f;
  }
#pragma unroll
  for (int r = 0; r < 4; ++r) {
    int rl = w * 16 + quad * 4 + r;
    sOut[rl * 64 + 0 + l16] = f2bf(acc0[r] * dvr[r]);
    sOut[rl * 64 + 16 + l16] = f2bf(acc1[r] * dvr[r]);
    sOut[rl * 64 + 32 + l16] = f2bf(acc2[r] * dvr[r]);
    sOut[rl * 64 + 48 + l16] = f2bf(acc3[r] * dvr[r]);
  }
  __syncthreads();
#pragma unroll
  for (int p = 0; p < 2; ++p) {
    int q = t + 256 * p;
    int r = q >> 3, s = q & 7;
    int gr = rbase + r;
    if (gr < n)
      *(uint4*)&h1b[(size_t)gr * 64 + s * 8] = *(uint4*)&sOut[r * 64 + s * 8];
  }
}

// ======================= agg1: bf16 gather -> bf16 out, 32 lanes/node, unroll 8 ====

__launch_bounds__(256)
__global__ void k_agg1(const unsigned* __restrict__ h1p, const float* __restrict__ dinv,
                       const int* __restrict__ rp, const int* __restrict__ csr_src,
                       unsigned* __restrict__ agg1b, int n) {
  int gid = blockIdx.x * 256 + threadIdx.x;
  int v = gid >> 5, f2 = gid & 31;  // uint index within row (2 feats)
  if (v >= n) return;
  int beg = rp[v], end = rp[v + 1];
  unsigned w0 = h1p[(size_t)v * 32 + f2];  // self
  float ax0 = bflo(w0), ay0 = bfhi(w0);
  float ax1 = 0.f, ay1 = 0.f, ax2 = 0.f, ay2 = 0.f, ax3 = 0.f, ay3 = 0.f;
  float ax4 = 0.f, ay4 = 0.f, ax5 = 0.f, ay5 = 0.f, ax6 = 0.f, ay6 = 0.f;
  float ax7 = 0.f, ay7 = 0.f;
  for (int j = beg; j < end; j += 8) {
    int s0 = csr_src[j];
    int s1 = csr_src[j + 1];
    int s2 = csr_src[j + 2];
    int s3 = csr_src[j + 3];
    int s4 = csr_src[j + 4];
    int s5 = csr_src[j + 5];
    int s6 = csr_src[j + 6];
    int s7 = csr_src[j + 7];
    s1 = (j + 1 < end) ? s1 : n;
    s2 = (j + 2 < end) ? s2 : n;
    s3 = (j + 3 < end) ? s3 : n;
    s4 = (j + 4 < end) ? s4 : n;
    s5 = (j + 5 < end) ? s5 : n;
    s6 = (j + 6 < end) ? s6 : n;
    s7 = (j + 7 < end) ? s7 : n;
    unsigned g0 = h1p[(size_t)s0 * 32 + f2];
    unsigned g1 = h1p[(size_t)s1 * 32 + f2];
    unsigned g2 = h1p[(size_t)s2 * 32 + f2];
    unsigned g3 = h1p[(size_t)s3 * 32 + f2];
    unsigned g4 = h1p[(size_t)s4 * 32 + f2];
    unsigned g5 = h1p[(size_t)s5 * 32 + f2];
    unsigned g6 = h1p[(size_t)s6 * 32 + f2];
    unsigned g7 = h1p[(size_t)s7 * 32 + f2];
    ax0 += bflo(g0); ay0 += bfhi(g0);
    ax1 += bflo(g1); ay1 += bfhi(g1);
    ax2 += bflo(g2); ay2 += bfhi(g2);
    ax3 += bflo(g3); ay3 += bfhi(g3);
    ax4 += bflo(g4); ay4 += bfhi(g4);
    ax5 += bflo(g5); ay5 += bfhi(g5);
    ax6 += bflo(g6); ay6 += bfhi(g6);
    ax7 += bflo(g7); ay7 += bfhi(g7);
  }
  float dv = dinv[v];
  float sx = ((ax0 + ax1) + (ax2 + ax3)) + ((ax4 + ax5) + (ax6 + ax7));
  float sy = ((ay0 + ay1) + (ay2 + ay3)) + ((ay4 + ay5) + (ay6 + ay7));
  agg1b[(size_t)v * 32 + f2] = pk2(dv * sx, dv * sy);
}

// ======================= GEMM2 (MFMA): h2b[n][32](bf16) = dinv*(relu(agg1+b1)@W2^T)

__launch_bounds__(256)
__global__ void k_gemm2(const unsigned* __restrict__ agg1b, const float* __restrict__ b1,
                        const float* __restrict__ W2, const float* __restrict__ dinv,
                        unsigned short* __restrict__ h2b, int n) {
  __shared__ uint4 sXb[64 * 8];                        // 8 KB: 64 rows x 64k bf16
  __shared__ uint4 sWb[32 * 8];                        // 4 KB: 32 cols x 64k bf16
  __shared__ __align__(16) unsigned short sOut[64 * 32];  // 4 KB
  int t = threadIdx.x;
  int rbase = blockIdx.x * 64;
  const uint4* a4 = (const uint4*)agg1b;  // row = 8 uint4 (64 bf16)
  const float4* b14 = (const float4*)b1;
  const float4* W24 = (const float4*)W2;
#pragma unroll
  for (int p = 0; p < 2; ++p) {
    int q = t + 256 * p;
    int r = q >> 3, s = q & 7;
    int gr = rbase + r;
    uint4 o = make_uint4(0u, 0u, 0u, 0u);
    if (gr < n) {
      uint4 a = a4[(size_t)gr * 8 + s];
      float4 blo = b14[s * 2], bhi = b14[s * 2 + 1];
      o.x = pk2(fmaxf(bflo(a.x) + blo.x, 0.f), fmaxf(bfhi(a.x) + blo.y, 0.f));
      o.y = pk2(fmaxf(bflo(a.y) + blo.z, 0.f), fmaxf(bfhi(a.y) + blo.w, 0.f));
      o.z = pk2(fmaxf(bflo(a.z) + bhi.x, 0.f), fmaxf(bfhi(a.z) + bhi.y, 0.f));
      o.w = pk2(fmaxf(bflo(a.w) + bhi.z, 0.f), fmaxf(bfhi(a.w) + bhi.w, 0.f));
    }
    sXb[r * 8 + (s ^ (r & 7))] = o;
  }
  {
    int c = t >> 3, s = t & 7;
    float4 v0 = W24[c * 16 + s * 2];
    float4 v1 = W24[c * 16 + s * 2 + 1];
    uint4 pk;
    pk.x = pk2(v0.x, v0.y);
    pk.y = pk2(v0.z, v0.w);
    pk.z = pk2(v1.x, v1.y);
    pk.w = pk2(v1.z, v1.w);
    sWb[c * 8 + (s ^ (c & 7))] = pk;
  }
  __syncthreads();
  int lane = t & 63;
  int w = t >> 6;
  int l16 = lane & 15, quad = lane >> 4;
  int arow = w * 16 + l16;
  f32x4 acc0 = {0.f, 0.f, 0.f, 0.f};
  f32x4 acc1 = {0.f, 0.f, 0.f, 0.f};
#pragma unroll
  for (int kc = 0; kc < 2; ++kc) {
    int slot = kc * 4 + quad;
    uint4 ua = sXb[arow * 8 + (slot ^ (arow & 7))];
    bf16x8 a = *(bf16x8*)&ua;
    uint4 ub0 = sWb[l16 * 8 + (slot ^ (l16 & 7))];
    uint4 ub1 = sWb[(16 + l16) * 8 + (slot ^ (l16 & 7))];
    acc0 = __builtin_amdgcn_mfma_f32_16x16x32_bf16(a, *(bf16x8*)&ub0, acc0, 0, 0, 0);
    acc1 = __builtin_amdgcn_mfma_f32_16x16x32_bf16(a, *(bf16x8*)&ub1, acc1, 0, 0, 0);
  }
  float dvr[4];
#pragma unroll
  for (int r = 0; r < 4; ++r) {
    int grow = rbase + w * 16 + quad * 4 + r;
    dvr[r] = (grow < n) ? dinv[grow] : 0.f;
  }
#pragma unroll
  for (int r = 0; r < 4; ++r) {
    int rl = w * 16 + quad * 4 + r;
    sOut[rl * 32 + l16] = f2bf(acc0[r] * dvr[r]);
    sOut[rl * 32 + 16 + l16] = f2bf(acc1[r] * dvr[r]);
  }
  __syncthreads();
  {
    int r = t >> 2, s = t & 3;
    int gr = rbase + r;
    if (gr < n)
      *(uint4*)&h2b[(size_t)gr * 32 + s * 8] = *(uint4*)&sOut[r * 32 + s * 8];
  }
}

// ======================= agg2: bf16 gather, 16 lanes/node x 2 feats, unroll 8 ======

__launch_bounds__(256)
__global__ void k_agg2(const unsigned* __restrict__ h2p, const float* __restrict__ dinv,
                       const int* __restrict__ rp, const int* __restrict__ csr_src,
                       const float* __restrict__ b2, float* __restrict__ out, int n) {
  int gid = blockIdx.x * 256 + threadIdx.x;
  int v = gid >> 4, f2 = gid & 15;  // uint index within row (2 feats)
  if (v >= n) return;
  int beg = rp[v], end = rp[v + 1];
  unsigned w0 = h2p[(size_t)v * 16 + f2];  // self
  float ax0 = bflo(w0), ay0 = bfhi(w0);
  float ax1 = 0.f, ay1 = 0.f, ax2 = 0.f, ay2 = 0.f, ax3 = 0.f, ay3 = 0.f;
  float ax4 = 0.f, ay4 = 0.f, ax5 = 0.f, ay5 = 0.f, ax6 = 0.f, ay6 = 0.f;
  float ax7 = 0.f, ay7 = 0.f;
  for (int j = beg; j < end; j += 8) {
    int s0 = csr_src[j];
    int s1 = csr_src[j + 1];
    int s2 = csr_src[j + 2];
    int s3 = csr_src[j + 3];
    int s4 = csr_src[j + 4];
    int s5 = csr_src[j + 5];
    int s6 = csr_src[j + 6];
    int s7 = csr_src[j + 7];
    s1 = (j + 1 < end) ? s1 : n;
    s2 = (j + 2 < end) ? s2 : n;
    s3 = (j + 3 < end) ? s3 : n;
    s4 = (j + 4 < end) ? s4 : n;
    s5 = (j + 5 < end) ? s5 : n;
    s6 = (j + 6 < end) ? s6 : n;
    s7 = (j + 7 < end) ? s7 : n;
    unsigned g0 = h2p[(size_t)s0 * 16 + f2];
    unsigned g1 = h2p[(size_t)s1 * 16 + f2];
    unsigned g2 = h2p[(size_t)s2 * 16 + f2];
    unsigned g3 = h2p[(size_t)s3 * 16 + f2];
    unsigned g4 = h2p[(size_t)s4 * 16 + f2];
    unsigned g5 = h2p[(size_t)s5 * 16 + f2];
    unsigned g6 = h2p[(size_t)s6 * 16 + f2];
    unsigned g7 = h2p[(size_t)s7 * 16 + f2];
    ax0 += bflo(g0); ay0 += bfhi(g0);
    ax1 += bflo(g1); ay1 += bfhi(g1);
    ax2 += bflo(g2); ay2 += bfhi(g2);
    ax3 += bflo(g3); ay3 += bfhi(g3);
    ax4 += bflo(g4); ay4 += bfhi(g4);
    ax5 += bflo(g5); ay5 += bfhi(g5);
    ax6 += bflo(g6); ay6 += bfhi(g6);
    ax7 += bflo(g7); ay7 += bfhi(g7);
  }
  float dv = dinv[v];
  float sx = ((ax0 + ax1) + (ax2 + ax3)) + ((ax4 + ax5) + (ax6 + ax7));
  float sy = ((ay0 + ay1) + (ay2 + ay3)) + ((ay4 + ay5) + (ay6 + ay7));
  float2 bv = *(const float2*)&b2[f2 * 2];
  *(float2*)&out[(size_t)v * 32 + f2 * 2] =
      make_float2(fmaf(dv, sx, bv.x), fmaf(dv, sy, bv.y));
}

// ======================= launcher =======================

extern "C" void kernel_launch(void* const* d_in, const int* in_sizes, int n_in,
                              void* d_out, int out_size, void* d_ws, size_t ws_size,
                              hipStream_t stream) {
  const float* x = (const float*)d_in[0];
  const int* ei = (const int*)d_in[1];
  const float* W1 = (const float*)d_in[2];
  const float* b1 = (const float*)d_in[3];
  const float* W2 = (const float*)d_in[4];
  const float* b2 = (const float*)d_in[5];
  float* out = (float*)d_out;

  const int n = in_sizes[0] / 128;  // 100000
  const int e = in_sizes[1] / 2;    // 1600000
  const int* src = ei;
  const int* dst = ei + e;

  const int NB = (n + 127) >> 7;          // coarse buckets (782)
  const int m = NB * G1;                  // count-matrix size
  const int chunk = (e + G1 - 1) / G1;    // edges per partition block
  const int NC = (m + 1 + 4095) / 4096;   // scan chunks (4096/block)

  char* base = (char*)d_ws;
  size_t off = 0;
  auto alloc = [&](size_t bytes) {
    char* p = base + off;
    off = (off + bytes + 255) & ~(size_t)255;
    return p;
  };
  int* C = (int*)alloc((size_t)m * 4);
  int* Cs = (int*)alloc((size_t)(m + 1) * 4);
  int* bsum = (int*)alloc(1024 * 4);
  int* bpack = (int*)alloc((size_t)e * 4);
  int* rp = (int*)alloc((size_t)(n + 1) * 4);
  int* csr_src = (int*)alloc((size_t)(e + 8) * 4);  // +8 pad for unrolled reads
  float* dinv = (float*)alloc((size_t)n * 4);
  unsigned short* h1b = (unsigned short*)alloc((size_t)(n + 1) * 64 * 2);  // bf16
  unsigned* agg1b = (unsigned*)alloc((size_t)n * 64 * 2);                  // bf16
  unsigned short* h2b = (unsigned short*)alloc((size_t)(n + 1) * 32 * 2);  // bf16

  // CSR build (no global atomics)
  k_zrow<<<1, 64, 0, stream>>>((unsigned*)h1b, (unsigned*)h2b, n);
  k_pcount<<<G1, 256, 0, stream>>>(dst, C, e, NB, chunk);
  k_scan_chunk<<<NC, 256, 0, stream>>>(C, Cs, bsum, m);
  k_scan_bsum<<<1, 256, 0, stream>>>(bsum, NC);
  k_add<<<(m + 255) / 256, 256, 0, stream>>>(Cs, bsum, m);
  k_partition<<<G1, 256, 0, stream>>>(src, dst, Cs, bpack, e, NB, chunk);
  k_bucket_csr<<<NB, 256, 0, stream>>>(bpack, Cs, rp, dinv, csr_src, n, e, NB);

  // layer 1
  k_gemm1<<<(n + 63) / 64, 256, 0, stream>>>(x, W1, dinv, h1b, n);
  {
    long long total = (long long)n * 32;
    k_agg1<<<(int)((total + 255) / 256), 256, 0, stream>>>((const unsigned*)h1b, dinv,
                                                           rp, csr_src, agg1b, n);
  }

  // layer 2
  k_gemm2<<<(n + 63) / 64, 256, 0, stream>>>(agg1b, b1, W2, dinv, h2b, n);
  {
    long long total = (long long)n * 16;
    k_agg2<<<(int)((total + 255) / 256), 256, 0, stream>>>((const unsigned*)h2b, dinv,
                                                           rp, csr_src, b2, out, n);
  }
}

// Round 14
// 208.573 us; speedup vs baseline: 1.0799x; 1.0799x over previous
//
#include <hip/hip_runtime.h>

#define THREADS 256
#define G1 256          // partition blocks
#define MAXNB 4096      // max coarse buckets (n <= 512k)
#define BCAP 2688       // LDS edge buffer for single-pass bucket CSR

using bf16x8 = __attribute__((ext_vector_type(8))) short;
using f32x4 = __attribute__((ext_vector_type(4))) float;

// bf16 helpers (self-contained, RNE)
static __device__ __forceinline__ unsigned short f2bf(float f) {
  unsigned u = __float_as_uint(f);
  unsigned r = (u + 0x7fff + ((u >> 16) & 1)) >> 16;
  return (unsigned short)r;
}
static __device__ __forceinline__ float bflo(unsigned w) {
  return __uint_as_float(w << 16);
}
static __device__ __forceinline__ float bfhi(unsigned w) {
  return __uint_as_float(w & 0xffff0000u);
}
static __device__ __forceinline__ unsigned pk2(float a, float b) {
  return (unsigned)f2bf(a) | ((unsigned)f2bf(b) << 16);
}

// ======================= scan machinery (chunk=1024, 4/thread) =====================

__global__ void k_scan_chunk(const int* __restrict__ cnt, int* __restrict__ rp,
                             int* __restrict__ bsum, int m) {
  __shared__ int s[256];
  int b = blockIdx.x, t = threadIdx.x;
  int base = b * 1024 + t * 4;
  int v[4];
  int sum = 0;
#pragma unroll
  for (int k = 0; k < 4; ++k) {
    int i = base + k;
    v[k] = (i < m) ? cnt[i] : 0;
    sum += v[k];
  }
  s[t] = sum;
  __syncthreads();
  int mine = sum;
  for (int off = 1; off < 256; off <<= 1) {
    int y = (t >= off) ? s[t - off] : 0;
    __syncthreads();
    s[t] += y;
    __syncthreads();
  }
  int run = s[t] - mine;
  if (t == 255) bsum[b] = s[255];
#pragma unroll
  for (int k = 0; k < 4; ++k) {
    int i = base + k;
    if (i <= m) rp[i] = run;
    run += v[k];
  }
}

__global__ void k_scan_bsum(int* __restrict__ bsum, int nb) {
  __shared__ int s[256];
  int t = threadIdx.x;
  int v = (t < nb) ? bsum[t] : 0;
  s[t] = v;
  __syncthreads();
  for (int off = 1; off < 256; off <<= 1) {
    int y = (t >= off) ? s[t - off] : 0;
    __syncthreads();
    s[t] += y;
    __syncthreads();
  }
  if (t < nb) bsum[t] = s[t] - v;
}

// ======================= CSR build: two-phase partition, LDS atomics only ===========
// pcount also zeroes the h1b/h2b guard rows (block 0) — replaces k_zrow launch.

__launch_bounds__(256)
__global__ void k_pcount(const int* __restrict__ dst, int* __restrict__ C, int e,
                         int NB, int chunk, unsigned* __restrict__ h1b,
                         unsigned* __restrict__ h2b, int n) {
  __shared__ int h[MAXNB];
  int blk = blockIdx.x, t = threadIdx.x;
  if (blk == 0) {
    if (t < 16) h1b[(size_t)n * 32 + t] = 0u;
    else if (t < 24) h2b[(size_t)n * 16 + (t - 16)] = 0u;
  }
  for (int i = t; i < NB; i += 256) h[i] = 0;
  __syncthreads();
  int beg = blk * chunk;
  int stop = min(e, beg + chunk);
  for (int j = beg + t; j < stop; j += 256) atomicAdd(&h[dst[j] >> 7], 1);
  __syncthreads();
  for (int i = t; i < NB; i += 256) C[i * G1 + blk] = h[i];
}

// partition applies the bsum add itself (k_add eliminated)
__launch_bounds__(256)
__global__ void k_partition(const int* __restrict__ src, const int* __restrict__ dst,
                            const int* __restrict__ Cs, const int* __restrict__ bsum,
                            int* __restrict__ bpack, int e, int NB, int chunk) {
  __shared__ int cur[MAXNB];
  int blk = blockIdx.x, t = threadIdx.x;
  for (int i = t; i < NB; i += 256) {
    int f = i * G1 + blk;
    cur[i] = Cs[f] + bsum[f >> 10];
  }
  __syncthreads();
  int beg = blk * chunk;
  int stop = min(e, beg + chunk);
  for (int j = beg + t; j < stop; j += 256) {
    int d = dst[j];
    int b = d >> 7;
    int pos = atomicAdd(&cur[b], 1);
    bpack[pos] = (src[j] << 7) | (d & 127);
  }
}

// single-pass: bucket edges cached in LDS (fallback to two-pass if oversized)
__launch_bounds__(256)
__global__ void k_bucket_csr(const int* __restrict__ bpack, const int* __restrict__ Cs,
                             const int* __restrict__ bsum, int* __restrict__ rp,
                             float* __restrict__ dinv, int* __restrict__ csr_src,
                             int n, int e, int NB) {
  __shared__ int cl[128];
  __shared__ int cur[128];
  __shared__ int buf[BCAP];
  int blk = blockIdx.x, t = threadIdx.x;
  int fb = blk * G1;
  int base = Cs[fb] + bsum[fb >> 10];
  int end;
  if (blk == NB - 1) {
    end = e;
  } else {
    int fe = (blk + 1) * G1;
    end = Cs[fe] + bsum[fe >> 10];
  }
  int cnt = end - base;
  if (t < 128) cl[t] = 0;
  __syncthreads();
  if (cnt <= BCAP) {
    for (int j = base + t; j < end; j += 256) {
      int p = bpack[j];
      buf[j - base] = p;
      atomicAdd(&cl[p & 127], 1);
    }
  } else {
    for (int j = base + t; j < end; j += 256) atomicAdd(&cl[bpack[j] & 127], 1);
  }
  __syncthreads();
  int own = (t < 128) ? cl[t] : 0;
  for (int off = 1; off < 128; off <<= 1) {
    int y = (t >= off && t < 128) ? cl[t - off] : 0;
    __syncthreads();
    if (t < 128) cl[t] += y;
    __syncthreads();
  }
  if (t < 128) {
    int excl = cl[t] - own;
    int v = (blk << 7) + t;
    if (v < n) {
      rp[v] = base + excl;
      dinv[v] = rsqrtf((float)own + 1.0f);
    }
    cur[t] = base + excl;
  }
  __syncthreads();
  if (cnt <= BCAP) {
    for (int j = t; j < cnt; j += 256) {
      int p = buf[j];
      int pos = atomicAdd(&cur[p & 127], 1);
      csr_src[pos] = p >> 7;
    }
  } else {
    for (int j = base + t; j < end; j += 256) {
      int p = bpack[j];
      int pos = atomicAdd(&cur[p & 127], 1);
      csr_src[pos] = p >> 7;
    }
  }
  if (blk == 0 && t == 0) rp[n] = e;
}

// ======================= GEMM1 (MFMA): h1b[n][64](bf16) = dinv[r]*(x @ W1^T) ======

__launch_bounds__(256)
__global__ void k_gemm1(const float* __restrict__ x, const float* __restrict__ W1,
                        const float* __restrict__ dinv, unsigned short* __restrict__ h1b,
                        int n) {
  __shared__ uint4 sXb[64 * 16];                       // 16 KB
  __shared__ uint4 sWb[64 * 16];                       // 16 KB
  __shared__ __align__(16) unsigned short sOut[64 * 64];  // 8 KB
  int t = threadIdx.x;
  const float4* x4 = (const float4*)x;
  const float4* W14 = (const float4*)W1;
  int rbase = blockIdx.x * 64;
#pragma unroll
  for (int p = 0; p < 4; ++p) {
    int q = t + 256 * p;
    int r = q >> 4, s = q & 15;
    int gr = rbase + r;
    float4 v0 = make_float4(0.f, 0.f, 0.f, 0.f), v1 = v0;
    if (gr < n) {
      v0 = x4[(size_t)gr * 32 + s * 2];
      v1 = x4[(size_t)gr * 32 + s * 2 + 1];
    }
    uint4 pk;
    pk.x = pk2(v0.x, v0.y);
    pk.y = pk2(v0.z, v0.w);
    pk.z = pk2(v1.x, v1.y);
    pk.w = pk2(v1.z, v1.w);
    sXb[r * 16 + (s ^ (r & 15))] = pk;
  }
#pragma unroll
  for (int p = 0; p < 4; ++p) {
    int q = t + 256 * p;
    int c = q >> 4, s = q & 15;
    float4 v0 = W14[c * 32 + s * 2];
    float4 v1 = W14[c * 32 + s * 2 + 1];
    uint4 pk;
    pk.x = pk2(v0.x, v0.y);
    pk.y = pk2(v0.z, v0.w);
    pk.z = pk2(v1.x, v1.y);
    pk.w = pk2(v1.z, v1.w);
    sWb[c * 16 + (s ^ (c & 15))] = pk;
  }
  __syncthreads();
  int lane = t & 63;
  int w = t >> 6;
  int l16 = lane & 15, quad = lane >> 4;
  int arow = w * 16 + l16;
  f32x4 acc0 = {0.f, 0.f, 0.f, 0.f};
  f32x4 acc1 = {0.f, 0.f, 0.f, 0.f};
  f32x4 acc2 = {0.f, 0.f, 0.f, 0.f};
  f32x4 acc3 = {0.f, 0.f, 0.f, 0.f};
#pragma unroll
  for (int kc = 0; kc < 4; ++kc) {
    int slot = kc * 4 + quad;
    uint4 ua = sXb[arow * 16 + (slot ^ (arow & 15))];
    bf16x8 a = *(bf16x8*)&ua;
    uint4 ub0 = sWb[(0 + l16) * 16 + (slot ^ l16)];
    uint4 ub1 = sWb[(16 + l16) * 16 + (slot ^ l16)];
    uint4 ub2 = sWb[(32 + l16) * 16 + (slot ^ l16)];
    uint4 ub3 = sWb[(48 + l16) * 16 + (slot ^ l16)];
    acc0 = __builtin_amdgcn_mfma_f32_16x16x32_bf16(a, *(bf16x8*)&ub0, acc0, 0, 0, 0);
    acc1 = __builtin_amdgcn_mfma_f32_16x16x32_bf16(a, *(bf16x8*)&ub1, acc1, 0, 0, 0);
    acc2 = __builtin_amdgcn_mfma_f32_16x16x32_bf16(a, *(bf16x8*)&ub2, acc2, 0, 0, 0);
    acc3 = __builtin_amdgcn_mfma_f32_16x16x32_bf16(a, *(bf16x8*)&ub3, acc3, 0, 0, 0);
  }
  float dvr[4];
#pragma unroll
  for (int r = 0; r < 4; ++r) {
    int grow = rbase + w * 16 + quad * 4 + r;
    dvr[r] = (grow < n) ? dinv[grow] : 0.f;
  }
#pragma unroll
  for (int r = 0; r < 4; ++r) {
    int rl = w * 16 + quad * 4 + r;
    sOut[rl * 64 + 0 + l16] = f2bf(acc0[r] * dvr[r]);
    sOut[rl * 64 + 16 + l16] = f2bf(acc1[r] * dvr[r]);
    sOut[rl * 64 + 32 + l16] = f2bf(acc2[r] * dvr[r]);
    sOut[rl * 64 + 48 + l16] = f2bf(acc3[r] * dvr[r]);
  }
  __syncthreads();
#pragma unroll
  for (int p = 0; p < 2; ++p) {
    int q = t + 256 * p;
    int r = q >> 3, s = q & 7;
    int gr = rbase + r;
    if (gr < n)
      *(uint4*)&h1b[(size_t)gr * 64 + s * 8] = *(uint4*)&sOut[r * 64 + s * 8];
  }
}

// ======================= agg1: bf16 gather -> bf16 out, 32 lanes/node, unroll 8 ====

__launch_bounds__(256)
__global__ void k_agg1(const unsigned* __restrict__ h1p, const float* __restrict__ dinv,
                       const int* __restrict__ rp, const int* __restrict__ csr_src,
                       unsigned* __restrict__ agg1b, int n) {
  int gid = blockIdx.x * 256 + threadIdx.x;
  int v = gid >> 5, f2 = gid & 31;  // uint index within row (2 feats)
  if (v >= n) return;
  int beg = rp[v], end = rp[v + 1];
  unsigned w0 = h1p[(size_t)v * 32 + f2];  // self
  float ax0 = bflo(w0), ay0 = bfhi(w0);
  float ax1 = 0.f, ay1 = 0.f, ax2 = 0.f, ay2 = 0.f, ax3 = 0.f, ay3 = 0.f;
  float ax4 = 0.f, ay4 = 0.f, ax5 = 0.f, ay5 = 0.f, ax6 = 0.f, ay6 = 0.f;
  float ax7 = 0.f, ay7 = 0.f;
  for (int j = beg; j < end; j += 8) {
    int s0 = csr_src[j];
    int s1 = csr_src[j + 1];
    int s2 = csr_src[j + 2];
    int s3 = csr_src[j + 3];
    int s4 = csr_src[j + 4];
    int s5 = csr_src[j + 5];
    int s6 = csr_src[j + 6];
    int s7 = csr_src[j + 7];
    s1 = (j + 1 < end) ? s1 : n;
    s2 = (j + 2 < end) ? s2 : n;
    s3 = (j + 3 < end) ? s3 : n;
    s4 = (j + 4 < end) ? s4 : n;
    s5 = (j + 5 < end) ? s5 : n;
    s6 = (j + 6 < end) ? s6 : n;
    s7 = (j + 7 < end) ? s7 : n;
    unsigned g0 = h1p[(size_t)s0 * 32 + f2];
    unsigned g1 = h1p[(size_t)s1 * 32 + f2];
    unsigned g2 = h1p[(size_t)s2 * 32 + f2];
    unsigned g3 = h1p[(size_t)s3 * 32 + f2];
    unsigned g4 = h1p[(size_t)s4 * 32 + f2];
    unsigned g5 = h1p[(size_t)s5 * 32 + f2];
    unsigned g6 = h1p[(size_t)s6 * 32 + f2];
    unsigned g7 = h1p[(size_t)s7 * 32 + f2];
    ax0 += bflo(g0); ay0 += bfhi(g0);
    ax1 += bflo(g1); ay1 += bfhi(g1);
    ax2 += bflo(g2); ay2 += bfhi(g2);
    ax3 += bflo(g3); ay3 += bfhi(g3);
    ax4 += bflo(g4); ay4 += bfhi(g4);
    ax5 += bflo(g5); ay5 += bfhi(g5);
    ax6 += bflo(g6); ay6 += bfhi(g6);
    ax7 += bflo(g7); ay7 += bfhi(g7);
  }
  float dv = dinv[v];
  float sx = ((ax0 + ax1) + (ax2 + ax3)) + ((ax4 + ax5) + (ax6 + ax7));
  float sy = ((ay0 + ay1) + (ay2 + ay3)) + ((ay4 + ay5) + (ay6 + ay7));
  agg1b[(size_t)v * 32 + f2] = pk2(dv * sx, dv * sy);
}

// ======================= GEMM2 (MFMA): h2b[n][32](bf16) = dinv*(relu(agg1+b1)@W2^T)

__launch_bounds__(256)
__global__ void k_gemm2(const unsigned* __restrict__ agg1b, const float* __restrict__ b1,
                        const float* __restrict__ W2, const float* __restrict__ dinv,
                        unsigned short* __restrict__ h2b, int n) {
  __shared__ uint4 sXb[64 * 8];                        // 8 KB: 64 rows x 64k bf16
  __shared__ uint4 sWb[32 * 8];                        // 4 KB: 32 cols x 64k bf16
  __shared__ __align__(16) unsigned short sOut[64 * 32];  // 4 KB
  int t = threadIdx.x;
  int rbase = blockIdx.x * 64;
  const uint4* a4 = (const uint4*)agg1b;  // row = 8 uint4 (64 bf16)
  const float4* b14 = (const float4*)b1;
  const float4* W24 = (const float4*)W2;
#pragma unroll
  for (int p = 0; p < 2; ++p) {
    int q = t + 256 * p;
    int r = q >> 3, s = q & 7;
    int gr = rbase + r;
    uint4 o = make_uint4(0u, 0u, 0u, 0u);
    if (gr < n) {
      uint4 a = a4[(size_t)gr * 8 + s];
      float4 blo = b14[s * 2], bhi = b14[s * 2 + 1];
      o.x = pk2(fmaxf(bflo(a.x) + blo.x, 0.f), fmaxf(bfhi(a.x) + blo.y, 0.f));
      o.y = pk2(fmaxf(bflo(a.y) + blo.z, 0.f), fmaxf(bfhi(a.y) + blo.w, 0.f));
      o.z = pk2(fmaxf(bflo(a.z) + bhi.x, 0.f), fmaxf(bfhi(a.z) + bhi.y, 0.f));
      o.w = pk2(fmaxf(bflo(a.w) + bhi.z, 0.f), fmaxf(bfhi(a.w) + bhi.w, 0.f));
    }
    sXb[r * 8 + (s ^ (r & 7))] = o;
  }
  {
    int c = t >> 3, s = t & 7;
    float4 v0 = W24[c * 16 + s * 2];
    float4 v1 = W24[c * 16 + s * 2 + 1];
    uint4 pk;
    pk.x = pk2(v0.x, v0.y);
    pk.y = pk2(v0.z, v0.w);
    pk.z = pk2(v1.x, v1.y);
    pk.w = pk2(v1.z, v1.w);
    sWb[c * 8 + (s ^ (c & 7))] = pk;
  }
  __syncthreads();
  int lane = t & 63;
  int w = t >> 6;
  int l16 = lane & 15, quad = lane >> 4;
  int arow = w * 16 + l16;
  f32x4 acc0 = {0.f, 0.f, 0.f, 0.f};
  f32x4 acc1 = {0.f, 0.f, 0.f, 0.f};
#pragma unroll
  for (int kc = 0; kc < 2; ++kc) {
    int slot = kc * 4 + quad;
    uint4 ua = sXb[arow * 8 + (slot ^ (arow & 7))];
    bf16x8 a = *(bf16x8*)&ua;
    uint4 ub0 = sWb[l16 * 8 + (slot ^ (l16 & 7))];
    uint4 ub1 = sWb[(16 + l16) * 8 + (slot ^ (l16 & 7))];
    acc0 = __builtin_amdgcn_mfma_f32_16x16x32_bf16(a, *(bf16x8*)&ub0, acc0, 0, 0, 0);
    acc1 = __builtin_amdgcn_mfma_f32_16x16x32_bf16(a, *(bf16x8*)&ub1, acc1, 0, 0, 0);
  }
  float dvr[4];
#pragma unroll
  for (int r = 0; r < 4; ++r) {
    int grow = rbase + w * 16 + quad * 4 + r;
    dvr[r] = (grow < n) ? dinv[grow] : 0.f;
  }
#pragma unroll
  for (int r = 0; r < 4; ++r) {
    int rl = w * 16 + quad * 4 + r;
    sOut[rl * 32 + l16] = f2bf(acc0[r] * dvr[r]);
    sOut[rl * 32 + 16 + l16] = f2bf(acc1[r] * dvr[r]);
  }
  __syncthreads();
  {
    int r = t >> 2, s = t & 3;
    int gr = rbase + r;
    if (gr < n)
      *(uint4*)&h2b[(size_t)gr * 32 + s * 8] = *(uint4*)&sOut[r * 32 + s * 8];
  }
}

// ======================= agg2: bf16 gather, 16 lanes/node x 2 feats, unroll 8 ======

__launch_bounds__(256)
__global__ void k_agg2(const unsigned* __restrict__ h2p, const float* __restrict__ dinv,
                       const int* __restrict__ rp, const int* __restrict__ csr_src,
                       const float* __restrict__ b2, float* __restrict__ out, int n) {
  int gid = blockIdx.x * 256 + threadIdx.x;
  int v = gid >> 4, f2 = gid & 15;  // uint index within row (2 feats)
  if (v >= n) return;
  int beg = rp[v], end = rp[v + 1];
  unsigned w0 = h2p[(size_t)v * 16 + f2];  // self
  float ax0 = bflo(w0), ay0 = bfhi(w0);
  float ax1 = 0.f, ay1 = 0.f, ax2 = 0.f, ay2 = 0.f, ax3 = 0.f, ay3 = 0.f;
  float ax4 = 0.f, ay4 = 0.f, ax5 = 0.f, ay5 = 0.f, ax6 = 0.f, ay6 = 0.f;
  float ax7 = 0.f, ay7 = 0.f;
  for (int j = beg; j < end; j += 8) {
    int s0 = csr_src[j];
    int s1 = csr_src[j + 1];
    int s2 = csr_src[j + 2];
    int s3 = csr_src[j + 3];
    int s4 = csr_src[j + 4];
    int s5 = csr_src[j + 5];
    int s6 = csr_src[j + 6];
    int s7 = csr_src[j + 7];
    s1 = (j + 1 < end) ? s1 : n;
    s2 = (j + 2 < end) ? s2 : n;
    s3 = (j + 3 < end) ? s3 : n;
    s4 = (j + 4 < end) ? s4 : n;
    s5 = (j + 5 < end) ? s5 : n;
    s6 = (j + 6 < end) ? s6 : n;
    s7 = (j + 7 < end) ? s7 : n;
    unsigned g0 = h2p[(size_t)s0 * 16 + f2];
    unsigned g1 = h2p[(size_t)s1 * 16 + f2];
    unsigned g2 = h2p[(size_t)s2 * 16 + f2];
    unsigned g3 = h2p[(size_t)s3 * 16 + f2];
    unsigned g4 = h2p[(size_t)s4 * 16 + f2];
    unsigned g5 = h2p[(size_t)s5 * 16 + f2];
    unsigned g6 = h2p[(size_t)s6 * 16 + f2];
    unsigned g7 = h2p[(size_t)s7 * 16 + f2];
    ax0 += bflo(g0); ay0 += bfhi(g0);
    ax1 += bflo(g1); ay1 += bfhi(g1);
    ax2 += bflo(g2); ay2 += bfhi(g2);
    ax3 += bflo(g3); ay3 += bfhi(g3);
    ax4 += bflo(g4); ay4 += bfhi(g4);
    ax5 += bflo(g5); ay5 += bfhi(g5);
    ax6 += bflo(g6); ay6 += bfhi(g6);
    ax7 += bflo(g7); ay7 += bfhi(g7);
  }
  float dv = dinv[v];
  float sx = ((ax0 + ax1) + (ax2 + ax3)) + ((ax4 + ax5) + (ax6 + ax7));
  float sy = ((ay0 + ay1) + (ay2 + ay3)) + ((ay4 + ay5) + (ay6 + ay7));
  float2 bv = *(const float2*)&b2[f2 * 2];
  *(float2*)&out[(size_t)v * 32 + f2 * 2] =
      make_float2(fmaf(dv, sx, bv.x), fmaf(dv, sy, bv.y));
}

// ======================= launcher =======================

extern "C" void kernel_launch(void* const* d_in, const int* in_sizes, int n_in,
                              void* d_out, int out_size, void* d_ws, size_t ws_size,
                              hipStream_t stream) {
  const float* x = (const float*)d_in[0];
  const int* ei = (const int*)d_in[1];
  const float* W1 = (const float*)d_in[2];
  const float* b1 = (const float*)d_in[3];
  const float* W2 = (const float*)d_in[4];
  const float* b2 = (const float*)d_in[5];
  float* out = (float*)d_out;

  const int n = in_sizes[0] / 128;  // 100000
  const int e = in_sizes[1] / 2;    // 1600000
  const int* src = ei;
  const int* dst = ei + e;

  const int NB = (n + 127) >> 7;          // coarse buckets (782)
  const int m = NB * G1;                  // count-matrix size
  const int chunk = (e + G1 - 1) / G1;    // edges per partition block
  const int NC = (m + 1 + 1023) / 1024;   // scan chunks

  char* base = (char*)d_ws;
  size_t off = 0;
  auto alloc = [&](size_t bytes) {
    char* p = base + off;
    off = (off + bytes + 255) & ~(size_t)255;
    return p;
  };
  int* C = (int*)alloc((size_t)m * 4);
  int* Cs = (int*)alloc((size_t)(m + 1) * 4);
  int* bsum = (int*)alloc(1024 * 4);
  int* bpack = (int*)alloc((size_t)e * 4);
  int* rp = (int*)alloc((size_t)(n + 1) * 4);
  int* csr_src = (int*)alloc((size_t)(e + 8) * 4);  // +8 pad for unrolled reads
  float* dinv = (float*)alloc((size_t)n * 4);
  unsigned short* h1b = (unsigned short*)alloc((size_t)(n + 1) * 64 * 2);  // bf16
  unsigned* agg1b = (unsigned*)alloc((size_t)n * 64 * 2);                  // bf16
  unsigned short* h2b = (unsigned short*)alloc((size_t)(n + 1) * 32 * 2);  // bf16

  // CSR build (no global atomics); zrow folded into pcount; k_add eliminated
  k_pcount<<<G1, 256, 0, stream>>>(dst, C, e, NB, chunk, (unsigned*)h1b,
                                   (unsigned*)h2b, n);
  k_scan_chunk<<<NC, 256, 0, stream>>>(C, Cs, bsum, m);
  k_scan_bsum<<<1, 256, 0, stream>>>(bsum, NC);
  k_partition<<<G1, 256, 0, stream>>>(src, dst, Cs, bsum, bpack, e, NB, chunk);
  k_bucket_csr<<<NB, 256, 0, stream>>>(bpack, Cs, bsum, rp, dinv, csr_src, n, e, NB);

  // layer 1
  k_gemm1<<<(n + 63) / 64, 256, 0, stream>>>(x, W1, dinv, h1b, n);
  {
    long long total = (long long)n * 32;
    k_agg1<<<(int)((total + 255) / 256), 256, 0, stream>>>((const unsigned*)h1b, dinv,
                                                           rp, csr_src, agg1b, n);
  }

  // layer 2
  k_gemm2<<<(n + 63) / 64, 256, 0, stream>>>(agg1b, b1, W2, dinv, h2b, n);
  {
    long long total = (long long)n * 16;
    k_agg2<<<(int)((total + 255) / 256), 256, 0, stream>>>((const unsigned*)h2b, dinv,
                                                           rp, csr_src, b2, out, n);
  }
}